// Round 9
// baseline (108.594 us; speedup 1.0000x reference)
//
#include <hip/hip_runtime.h>

namespace {
constexpr int Hh = 16;
constexpr int Ll = 1024;
constexpr int Dd = 64;
constexpr int Cc = 64;                   // chunk length
constexpr int NCHUNK = Ll / Cc;          // 16
constexpr float PI_HALF = 1.5707963267948966f;
constexpr float EPSV = 1e-6f;
constexpr int KV_ELEMS = 64 * 128;       // bf16 elems per chunk state [d][f]
constexpr size_t KV_TOTAL_E = (size_t)Hh * NCHUNK * KV_ELEMS;
constexpr size_t KS_TOTAL_E = (size_t)Hh * NCHUNK * 128;
constexpr unsigned int MAGIC = 0x1B2C3D4Eu;   // != any repeated-byte poison
}

typedef __attribute__((ext_vector_type(8))) short short8;
typedef __attribute__((ext_vector_type(4))) float floatx4;

__device__ __forceinline__ unsigned short f2bf(float x) {
    unsigned int u = __float_as_uint(x);
    unsigned int r = u + 0x7fffu + ((u >> 16) & 1u);
    return (unsigned short)(r >> 16);
}
__device__ __forceinline__ float bf2f(unsigned short b) {
    return __uint_as_float(((unsigned int)b) << 16);
}

#define MFMA16(a, b, c) __builtin_amdgcn_mfma_f32_16x16x32_bf16((a), (b), (c), 0, 0, 0)

// ---------------------------------------------------------------------------
// SINGLE dispatch. Block (h,c), all 256 blocks co-resident (LDS 89 KB ->
// 1 block/CU; 256 blocks <= 256 CUs -> no deadlock possible).
//   stage q/k/v once (q->Aq, kf->Bk AND kf^T->Ak, V^T->Bv cols 0..63)
//   phase 1: own chunk state via MFMA (r8 cf_sums math, bones-ksum per r4)
//            -> direct bf16 stores to ws; threadfence; release MAGIC flag
//   phase 2: poll flags of chunks 0..c-1 (relaxed, then acquire fence),
//            fp32 prefix sum of bf16 states (r8 cf_out2 verbatim),
//            dump state->Bv[d][64+f], ksum->Bk row 64,
//            GEMM1 + mask + rowsum, GEMM2, store (r8 verbatim).
__global__ __launch_bounds__(256)
void cf_fused1(const float* __restrict__ qin, const float* __restrict__ kin,
               const float* __restrict__ vin,
               unsigned short* __restrict__ wskv, unsigned short* __restrict__ wsks,
               unsigned int* __restrict__ flags, float* __restrict__ out) {
    const int c = blockIdx.x, h = blockIdx.y;
    const int tid = threadIdx.x;
    constexpr int SA = 200, SB = 136, SV = 200, S1 = 72;
    __shared__ unsigned short Aq[64 * SA];   // [l][0..63 scores | 64..191 qf]
    __shared__ unsigned short Bk[80 * SB];   // [n=j][k=f]; row 64 = ksum; 65..79 = 0
    __shared__ unsigned short Bv[64 * SV];   // [n=d][0..63 V^T | 64..191 S]
    __shared__ unsigned short Ak[128 * S1];  // kf^T [f][j]  (phase 1 A-operand)

    const int wave = tid >> 6, lane = tid & 63;
    const int lrow = lane & 15, quad = lane >> 4;

    #pragma unroll
    for (int i = 0; i < 4; ++i) {            // zero Bk rows 65..79
        int z = i * 256 + tid;
        if (z < 1020) ((unsigned int*)Bk)[(65 * SB) / 2 + z] = 0u;
    }

    // ---- staging q,k,v ONCE (r8 staging + Ak transpose writes) ----
    const size_t gbase = ((size_t)h * Ll + (size_t)c * Cc) * Dd;
    const float4* q4 = (const float4*)(qin + gbase);
    const float4* k4 = (const float4*)(kin + gbase);
    const float4* v4 = (const float4*)(vin + gbase);
    #pragma unroll
    for (int i = 0; i < 4; ++i) {
        int e4 = i * 256 + tid;
        int j = e4 >> 4, d4 = (e4 & 15) * 4;
        float th = PI_HALF * (float)(c * Cc + j + 1) * (1.0f / (float)Ll);
        float sj, cj; __sincosf(th, &sj, &cj);
        float4 qv = q4[e4];
        float q0 = fmaxf(qv.x, 0.f), q1 = fmaxf(qv.y, 0.f);
        float q2 = fmaxf(qv.z, 0.f), q3 = fmaxf(qv.w, 0.f);
        *(ushort4*)&Aq[j * SA + 64 + d4] =
            make_ushort4(f2bf(q0 * sj), f2bf(q1 * sj), f2bf(q2 * sj), f2bf(q3 * sj));
        *(ushort4*)&Aq[j * SA + 128 + d4] =
            make_ushort4(f2bf(q0 * cj), f2bf(q1 * cj), f2bf(q2 * cj), f2bf(q3 * cj));
        float4 kx = k4[e4];
        float k0 = fmaxf(kx.x, 0.f), k1 = fmaxf(kx.y, 0.f);
        float k2 = fmaxf(kx.z, 0.f), k3 = fmaxf(kx.w, 0.f);
        unsigned short s0 = f2bf(k0 * sj), s1 = f2bf(k1 * sj);
        unsigned short s2 = f2bf(k2 * sj), s3 = f2bf(k3 * sj);
        unsigned short c0 = f2bf(k0 * cj), c1 = f2bf(k1 * cj);
        unsigned short c2 = f2bf(k2 * cj), c3 = f2bf(k3 * cj);
        *(ushort4*)&Bk[j * SB + d4] = make_ushort4(s0, s1, s2, s3);
        *(ushort4*)&Bk[j * SB + 64 + d4] = make_ushort4(c0, c1, c2, c3);
        Ak[(d4 + 0) * S1 + j] = s0;
        Ak[(d4 + 1) * S1 + j] = s1;
        Ak[(d4 + 2) * S1 + j] = s2;
        Ak[(d4 + 3) * S1 + j] = s3;
        Ak[(64 + d4 + 0) * S1 + j] = c0;
        Ak[(64 + d4 + 1) * S1 + j] = c1;
        Ak[(64 + d4 + 2) * S1 + j] = c2;
        Ak[(64 + d4 + 3) * S1 + j] = c3;
        float4 vx = v4[e4];
        Bv[(d4 + 0) * SV + j] = f2bf(vx.x);
        Bv[(d4 + 1) * SV + j] = f2bf(vx.y);
        Bv[(d4 + 2) * SV + j] = f2bf(vx.z);
        Bv[(d4 + 3) * SV + j] = f2bf(vx.w);
    }
    __syncthreads();

    // ---- phase 1: own chunk state + ksum via MFMA (bones per r4) ----
    short8 bones;
    {
        short o = (lrow == 0) ? (short)0x3F80 : (short)0;
        #pragma unroll
        for (int i = 0; i < 8; ++i) bones[i] = o;
    }
    unsigned short* kvout = wskv + (size_t)(h * NCHUNK + c) * KV_ELEMS;
    unsigned short* ksout = wsks + (size_t)(h * NCHUNK + c) * 128;
    #pragma unroll
    for (int t = 0; t < 2; ++t) {
        const int ft = wave * 2 + t;                     // f-tile 0..7
        short8 af[2];
        #pragma unroll
        for (int ks = 0; ks < 2; ++ks)
            af[ks] = *(const short8*)&Ak[(ft * 16 + lrow) * S1 + ks * 32 + quad * 8];
        #pragma unroll
        for (int nt = 0; nt < 5; ++nt) {
            floatx4 acc = {0.f, 0.f, 0.f, 0.f};
            #pragma unroll
            for (int ks = 0; ks < 2; ++ks) {
                short8 bf = (nt < 4)
                    ? *(const short8*)&Bv[(nt * 16 + lrow) * SV + ks * 32 + quad * 8]
                    : bones;
                acc = MFMA16(af[ks], bf, acc);
            }
            ushort4 pk = make_ushort4(f2bf(acc[0]), f2bf(acc[1]), f2bf(acc[2]), f2bf(acc[3]));
            if (nt < 4) {
                // state[d = nt*16+lrow][f = ft*16+quad*4 + r]
                *(ushort4*)(kvout + (nt * 16 + lrow) * 128 + ft * 16 + quad * 4) = pk;
            } else if (lrow == 0) {
                *(ushort4*)(ksout + ft * 16 + quad * 4) = pk;   // ksum (n=0 col)
            }
        }
    }
    __syncthreads();                       // all waves' stores drained (vmcnt 0)
    if (tid == 0) {
        __threadfence();                   // push this block's L2 to coherence pt
        __hip_atomic_store(&flags[h * NCHUNK + c], MAGIC,
                           __ATOMIC_RELEASE, __HIP_MEMORY_SCOPE_AGENT);
    }

    // ---- phase 2: wait for earlier chunks of this head ----
    if (c > 0 && tid < c) {
        while (__hip_atomic_load(&flags[h * NCHUNK + tid],
                                 __ATOMIC_RELAXED, __HIP_MEMORY_SCOPE_AGENT) != MAGIC)
            __builtin_amdgcn_s_sleep(2);
    }
    __syncthreads();
    if (c > 0) __threadfence();            // acquire: drop stale clean lines

    // ---- exclusive prefix: fp32 sum of chunk-states 0..c-1 (r8 verbatim) ----
    float facc[32];
    #pragma unroll
    for (int e = 0; e < 32; ++e) facc[e] = 0.f;
    const unsigned short* sbase = wskv + (size_t)h * NCHUNK * KV_ELEMS + tid * 32;
    if (c > 0) {
        short8 cur[4], nxt[4];
        #pragma unroll
        for (int i = 0; i < 4; ++i)
            cur[i] = *(const short8*)(sbase + i * 8);
        if (c > 1) {
            #pragma unroll
            for (int i = 0; i < 4; ++i)
                nxt[i] = *(const short8*)(sbase + KV_ELEMS + i * 8);
        }
        for (int cc = 0; cc < c; ++cc) {
            short8 fut[4];
            if (cc + 2 < c) {
                #pragma unroll
                for (int i = 0; i < 4; ++i)
                    fut[i] = *(const short8*)(sbase + (size_t)(cc + 2) * KV_ELEMS + i * 8);
            }
            #pragma unroll
            for (int i = 0; i < 4; ++i)
                #pragma unroll
                for (int e = 0; e < 8; ++e)
                    facc[i * 8 + e] += bf2f((unsigned short)cur[i][e]);
            #pragma unroll
            for (int i = 0; i < 4; ++i) { cur[i] = nxt[i]; nxt[i] = fut[i]; }
        }
    }
    float kacc = 0.f;
    if (tid < 128) {
        const unsigned short* kb = wsks + (size_t)h * NCHUNK * 128 + tid;
        for (int cc = 0; cc < c; ++cc) kacc += bf2f(kb[cc * 128]);
    }

    // ---- dump state -> Bv[d][64+f], ksum -> Bk row 64 ----
    {
        const int d = tid >> 2, f0 = (tid & 3) * 32;
        #pragma unroll
        for (int e8 = 0; e8 < 8; ++e8) {
            *(ushort4*)&Bv[d * SV + 64 + f0 + e8 * 4] =
                make_ushort4(f2bf(facc[e8 * 4 + 0]), f2bf(facc[e8 * 4 + 1]),
                             f2bf(facc[e8 * 4 + 2]), f2bf(facc[e8 * 4 + 3]));
        }
        if (tid < 128) Bk[64 * SB + tid] = f2bf(kacc);
    }
    __syncthreads();

    const int l0 = wave * 16;
    const int arow = (l0 + lrow) * SA;

    // ---- GEMM1: scores + denominator (r8 verbatim) ----
    short8 a1f[4];
    #pragma unroll
    for (int ks = 0; ks < 4; ++ks)
        a1f[ks] = *(const short8*)&Aq[arow + 64 + ks * 32 + quad * 8];
    floatx4 rs = {0.f, 0.f, 0.f, 0.f};
    #pragma unroll
    for (int nt = 0; nt < 5; ++nt) {
        floatx4 sc = {0.f, 0.f, 0.f, 0.f};
        #pragma unroll
        for (int ks = 0; ks < 4; ++ks) {
            short8 bf = *(const short8*)&Bk[(nt * 16 + lrow) * SB + ks * 32 + quad * 8];
            sc = MFMA16(a1f[ks], bf, sc);
        }
        if (nt < 4) {
            int j = nt * 16 + lrow;
            #pragma unroll
            for (int r = 0; r < 4; ++r) {
                int l = l0 + quad * 4 + r;
                float m = (j <= l) ? sc[r] : 0.f;
                sc[r] = m;
                Aq[l * SA + j] = f2bf(m);      // masked score -> A-layout for GEMM2
            }
        }
        rs += sc;                               // nt==4: rows 65..79 exact zeros
    }
    #pragma unroll
    for (int m = 1; m <= 8; m <<= 1) {          // row-sum across the 16 cols
        rs[0] += __shfl_xor(rs[0], m);
        rs[1] += __shfl_xor(rs[1], m);
        rs[2] += __shfl_xor(rs[2], m);
        rs[3] += __shfl_xor(rs[3], m);
    }
    float inv[4];
    #pragma unroll
    for (int r = 0; r < 4; ++r) inv[r] = 1.0f / fmaxf(rs[r], EPSV);

    __syncthreads();   // make this wave's score writes unambiguously visible

    // ---- GEMM2: O = [scores | qf] * [V ; S] (r8 verbatim) ----
    short8 sc0 = *(const short8*)&Aq[arow + 0 * 32 + quad * 8];
    short8 sc1 = *(const short8*)&Aq[arow + 1 * 32 + quad * 8];
    #pragma unroll
    for (int nt = 0; nt < 4; ++nt) {
        const int brow = (nt * 16 + lrow) * SV;
        floatx4 oacc = {0.f, 0.f, 0.f, 0.f};
        short8 b0 = *(const short8*)&Bv[brow + 0 * 32 + quad * 8];
        oacc = MFMA16(sc0, b0, oacc);
        short8 b1 = *(const short8*)&Bv[brow + 1 * 32 + quad * 8];
        oacc = MFMA16(sc1, b1, oacc);
        #pragma unroll
        for (int ks = 2; ks < 6; ++ks) {
            short8 bf = *(const short8*)&Bv[brow + ks * 32 + quad * 8];
            oacc = MFMA16(a1f[ks - 2], bf, oacc);
        }
        #pragma unroll
        for (int r = 0; r < 4; ++r) {
            int l = l0 + quad * 4 + r;
            out[gbase + (size_t)l * Dd + nt * 16 + lrow] = oacc[r] * inv[r];
        }
    }
}

extern "C" void kernel_launch(void* const* d_in, const int* in_sizes, int n_in,
                              void* d_out, int out_size, void* d_ws, size_t ws_size,
                              hipStream_t stream) {
    const float* q = (const float*)d_in[0];
    const float* k = (const float*)d_in[1];
    const float* v = (const float*)d_in[2];
    float* out = (float*)d_out;
    unsigned short* wskv = (unsigned short*)d_ws;             // [h][c][d][f] bf16
    unsigned short* wsks = wskv + KV_TOTAL_E;                 // [h][c][128] bf16
    unsigned int* flags = (unsigned int*)(wsks + KS_TOTAL_E); // [h][c] MAGIC flags
    dim3 grid(NCHUNK, Hh);
    cf_fused1<<<grid, 256, 0, stream>>>(q, k, v, wskv, wsks, flags, out);
}

// Round 10
// 74.923 us; speedup vs baseline: 1.4494x; 1.4494x over previous
//
#include <hip/hip_runtime.h>

namespace {
constexpr int Hh = 16;
constexpr int Ll = 1024;
constexpr int Dd = 64;
constexpr int Cc = 64;                   // chunk length
constexpr int NCHUNK = Ll / Cc;          // 16
constexpr float PI_HALF = 1.5707963267948966f;
constexpr float EPSV = 1e-6f;
constexpr int KV_ELEMS = 64 * 128;       // bf16 elems per chunk state [d][f]
constexpr size_t KV_TOTAL_E = (size_t)Hh * NCHUNK * KV_ELEMS;
}

typedef __attribute__((ext_vector_type(8))) short short8;
typedef __attribute__((ext_vector_type(4))) float floatx4;

__device__ __forceinline__ unsigned short f2bf(float x) {
    unsigned int u = __float_as_uint(x);
    unsigned int r = u + 0x7fffu + ((u >> 16) & 1u);
    return (unsigned short)(r >> 16);
}
__device__ __forceinline__ float bf2f(unsigned short b) {
    return __uint_as_float(((unsigned int)b) << 16);
}

#define MFMA16(a, b, c) __builtin_amdgcn_mfma_f32_16x16x32_bf16((a), (b), (c), 0, 0, 0)

// ---------------------------------------------------------------------------
// Kernel 1 (512 thr, 8 waves): per (h,c) chunk state via MFMA (verified math;
// each wave owns ONE f-tile). C[f][d]+ksum -> LDS [d][f] -> coalesced ws store.
__global__ __launch_bounds__(512)
void cf_sums(const float* __restrict__ kin, const float* __restrict__ vin,
             unsigned short* __restrict__ wskv, unsigned short* __restrict__ wsks) {
    const int c = blockIdx.x, h = blockIdx.y;
    const int tid = threadIdx.x;
    constexpr int S1 = 72, SC = 136;
    __shared__ unsigned short Ak[128 * S1];
    __shared__ unsigned short Bv1[80 * S1];
    __shared__ unsigned short Cst[64 * SC];
    __shared__ unsigned short Ks[128];

    const size_t gbase = ((size_t)h * Ll + (size_t)c * Cc) * Dd;
    const float4* k4 = (const float4*)(kin + gbase);
    const float4* v4 = (const float4*)(vin + gbase);
    #pragma unroll
    for (int i = 0; i < 2; ++i) {
        int e4 = i * 512 + tid;
        int j = e4 >> 4, d4 = (e4 & 15) * 4;
        float th = PI_HALF * (float)(c * Cc + j + 1) * (1.0f / (float)Ll);
        float sj, cj; __sincosf(th, &sj, &cj);
        float4 kx = k4[e4];
        float r0 = fmaxf(kx.x, 0.f), r1 = fmaxf(kx.y, 0.f);
        float r2 = fmaxf(kx.z, 0.f), r3 = fmaxf(kx.w, 0.f);
        Ak[(d4 + 0) * S1 + j] = f2bf(r0 * sj);
        Ak[(d4 + 1) * S1 + j] = f2bf(r1 * sj);
        Ak[(d4 + 2) * S1 + j] = f2bf(r2 * sj);
        Ak[(d4 + 3) * S1 + j] = f2bf(r3 * sj);
        Ak[(64 + d4 + 0) * S1 + j] = f2bf(r0 * cj);
        Ak[(64 + d4 + 1) * S1 + j] = f2bf(r1 * cj);
        Ak[(64 + d4 + 2) * S1 + j] = f2bf(r2 * cj);
        Ak[(64 + d4 + 3) * S1 + j] = f2bf(r3 * cj);
        float4 vx = v4[e4];
        Bv1[(d4 + 0) * S1 + j] = f2bf(vx.x);
        Bv1[(d4 + 1) * S1 + j] = f2bf(vx.y);
        Bv1[(d4 + 2) * S1 + j] = f2bf(vx.z);
        Bv1[(d4 + 3) * S1 + j] = f2bf(vx.w);
    }
    if (tid < 64) Bv1[64 * S1 + tid] = 0x3F80;           // ones column (bf16 1.0)
    if (tid >= 64 && tid < 72) Bv1[64 * S1 + tid] = 0;   // pad of ones row
    {
        int z = tid;                                     // zero rows 65..79
        if (z < 540) ((unsigned int*)Bv1)[(65 * S1) / 2 + z] = 0u;
        z = 512 + tid;
        if (z < 540) ((unsigned int*)Bv1)[(65 * S1) / 2 + z] = 0u;
    }
    __syncthreads();

    const int wave = tid >> 6, lane = tid & 63;
    const int lrow = lane & 15, quad = lane >> 4;
    {
        const int ft = wave;                             // f-tile 0..7
        short8 af[2];
        #pragma unroll
        for (int ks = 0; ks < 2; ++ks)
            af[ks] = *(const short8*)&Ak[(ft * 16 + lrow) * S1 + ks * 32 + quad * 8];
        #pragma unroll
        for (int nt = 0; nt < 5; ++nt) {
            floatx4 acc = {0.f, 0.f, 0.f, 0.f};
            #pragma unroll
            for (int ks = 0; ks < 2; ++ks) {
                short8 bf = *(const short8*)&Bv1[(nt * 16 + lrow) * S1 + ks * 32 + quad * 8];
                acc = MFMA16(af[ks], bf, acc);
            }
            ushort4 pk = make_ushort4(f2bf(acc[0]), f2bf(acc[1]), f2bf(acc[2]), f2bf(acc[3]));
            if (nt < 4) {
                // C[f][d] -> Cst[d][f]
                *(ushort4*)&Cst[(nt * 16 + lrow) * SC + ft * 16 + quad * 4] = pk;
            } else if (lrow == 0) {
                *(ushort4*)&Ks[ft * 16 + quad * 4] = pk;  // ksum column (n=64)
            }
        }
    }
    __syncthreads();

    unsigned short* kvout = wskv + (size_t)(h * NCHUNK + c) * KV_ELEMS;
    #pragma unroll
    for (int i = 0; i < 2; ++i) {
        int idx = i * 512 + tid;
        int row = idx >> 4, c8 = (idx & 15) * 8;
        *(uint4*)(kvout + row * 128 + c8) = *(const uint4*)&Cst[row * SC + c8];
    }
    if (tid < 16)
        *(uint4*)(wsks + (size_t)(h * NCHUNK + c) * 128 + tid * 8) =
            *(const uint4*)&Ks[tid * 8];
}

// ---------------------------------------------------------------------------
// Kernel 2: in-place EXCLUSIVE prefix scan across chunks — MLP rewrite:
// all 16 chunk values loaded upfront (independent, 16 in flight), prefix in
// registers, then 16 stores. Same fp32 accumulate / bf16 store order as the
// verified serial version. bx<32 -> state elems; bx==32 -> ksums.
__global__ __launch_bounds__(256)
void cf_scan(unsigned short* __restrict__ wskv, unsigned short* __restrict__ wsks) {
    const int bx = blockIdx.x, h = blockIdx.y;
    const int tid = threadIdx.x;
    if (bx < 32) {
        unsigned short* p = wskv + (size_t)h * NCHUNK * KV_ELEMS + bx * 256 + tid;
        unsigned short vals[NCHUNK];
        #pragma unroll
        for (int cc = 0; cc < NCHUNK; ++cc)
            vals[cc] = p[(size_t)cc * KV_ELEMS];          // 16 independent loads
        float run = 0.f;
        #pragma unroll
        for (int cc = 0; cc < NCHUNK; ++cc) {
            p[(size_t)cc * KV_ELEMS] = f2bf(run);
            run += bf2f(vals[cc]);
        }
    } else if (tid < 128) {
        unsigned short* p = wsks + (size_t)h * NCHUNK * 128 + tid;
        unsigned short vals[NCHUNK];
        #pragma unroll
        for (int cc = 0; cc < NCHUNK; ++cc)
            vals[cc] = p[cc * 128];
        float run = 0.f;
        #pragma unroll
        for (int cc = 0; cc < NCHUNK; ++cc) {
            p[cc * 128] = f2bf(run);
            run += bf2f(vals[cc]);
        }
    }
}

// ---------------------------------------------------------------------------
// Kernel 3 (512 thr): per (h,c) output. State+ksum prefetched into registers
// FIRST (latency hides under q/k/v staging); staging halved across 8 waves;
// GEMM1 (scores+denom) + GEMM2 on waves 0-3 (verified code).
__global__ __launch_bounds__(512)
void cf_out(const float* __restrict__ qin, const float* __restrict__ kin,
            const float* __restrict__ vin,
            const unsigned short* __restrict__ wskv,
            const unsigned short* __restrict__ wsks,
            float* __restrict__ out) {
    const int c = blockIdx.x, h = blockIdx.y;
    const int tid = threadIdx.x;
    constexpr int SA = 200, SB = 136, SV = 200;
    __shared__ unsigned short Aq[64 * SA];   // [l][0..63 scores | 64..191 qf]
    __shared__ unsigned short Bk[80 * SB];   // [n=j][k=f]; row 64 = ksum; 65..79 = 0
    __shared__ unsigned short Bv[64 * SV];   // [n=d][0..63 V^T | 64..191 S]

    const int wave = tid >> 6, lane = tid & 63;
    const int lrow = lane & 15, quad = lane >> 4;

    // ---- prefetch prefix state + ksum into registers (issued first) ----
    const uint4* s4g = (const uint4*)(wskv + (size_t)(h * NCHUNK + c) * KV_ELEMS);
    uint4 sreg0 = s4g[tid];
    uint4 sreg1 = s4g[512 + tid];
    uint4 kreg;
    if (tid < 16)
        kreg = ((const uint4*)(wsks + (size_t)(h * NCHUNK + c) * 128))[tid];

    {
        int z = tid;                             // zero Bk rows 65..79
        if (z < 1020) ((unsigned int*)Bk)[(65 * SB) / 2 + z] = 0u;
        z = 512 + tid;
        if (z < 1020) ((unsigned int*)Bk)[(65 * SB) / 2 + z] = 0u;
    }

    // ---- staging q,k,v of own chunk (verified; halved loops) ----
    const size_t gbase = ((size_t)h * Ll + (size_t)c * Cc) * Dd;
    const float4* q4 = (const float4*)(qin + gbase);
    const float4* k4 = (const float4*)(kin + gbase);
    const float4* v4 = (const float4*)(vin + gbase);
    #pragma unroll
    for (int i = 0; i < 2; ++i) {
        int e4 = i * 512 + tid;
        int j = e4 >> 4, d4 = (e4 & 15) * 4;
        float th = PI_HALF * (float)(c * Cc + j + 1) * (1.0f / (float)Ll);
        float sj, cj; __sincosf(th, &sj, &cj);
        float4 qv = q4[e4];
        float q0 = fmaxf(qv.x, 0.f), q1 = fmaxf(qv.y, 0.f);
        float q2 = fmaxf(qv.z, 0.f), q3 = fmaxf(qv.w, 0.f);
        *(ushort4*)&Aq[j * SA + 64 + d4] =
            make_ushort4(f2bf(q0 * sj), f2bf(q1 * sj), f2bf(q2 * sj), f2bf(q3 * sj));
        *(ushort4*)&Aq[j * SA + 128 + d4] =
            make_ushort4(f2bf(q0 * cj), f2bf(q1 * cj), f2bf(q2 * cj), f2bf(q3 * cj));
        float4 kx = k4[e4];
        float k0 = fmaxf(kx.x, 0.f), k1 = fmaxf(kx.y, 0.f);
        float k2 = fmaxf(kx.z, 0.f), k3 = fmaxf(kx.w, 0.f);
        *(ushort4*)&Bk[j * SB + d4] =
            make_ushort4(f2bf(k0 * sj), f2bf(k1 * sj), f2bf(k2 * sj), f2bf(k3 * sj));
        *(ushort4*)&Bk[j * SB + 64 + d4] =
            make_ushort4(f2bf(k0 * cj), f2bf(k1 * cj), f2bf(k2 * cj), f2bf(k3 * cj));
        float4 vx = v4[e4];
        Bv[(d4 + 0) * SV + j] = f2bf(vx.x);
        Bv[(d4 + 1) * SV + j] = f2bf(vx.y);
        Bv[(d4 + 2) * SV + j] = f2bf(vx.z);
        Bv[(d4 + 3) * SV + j] = f2bf(vx.w);
    }
    // state ws [d][f] -> Bv[d][64+f] (from registers); ksum -> Bk row 64
    {
        int idx = tid;
        *(uint4*)&Bv[(idx >> 4) * SV + 64 + (idx & 15) * 8] = sreg0;
        idx = 512 + tid;
        *(uint4*)&Bv[(idx >> 4) * SV + 64 + (idx & 15) * 8] = sreg1;
        if (tid < 16) *(uint4*)&Bk[64 * SB + tid * 8] = kreg;
    }
    __syncthreads();

    const int l0 = wave * 16;
    const int arow = (l0 + lrow) * SA;
    short8 a1f[4];
    float inv[4];

    // ---- GEMM1: scores + denominator (waves 0-3, verified) ----
    if (wave < 4) {
        #pragma unroll
        for (int ks = 0; ks < 4; ++ks)
            a1f[ks] = *(const short8*)&Aq[arow + 64 + ks * 32 + quad * 8];
        floatx4 rs = {0.f, 0.f, 0.f, 0.f};
        #pragma unroll
        for (int nt = 0; nt < 5; ++nt) {
            floatx4 sc = {0.f, 0.f, 0.f, 0.f};
            #pragma unroll
            for (int ks = 0; ks < 4; ++ks) {
                short8 bf = *(const short8*)&Bk[(nt * 16 + lrow) * SB + ks * 32 + quad * 8];
                sc = MFMA16(a1f[ks], bf, sc);
            }
            if (nt < 4) {
                int j = nt * 16 + lrow;
                #pragma unroll
                for (int r = 0; r < 4; ++r) {
                    int l = l0 + quad * 4 + r;
                    float m = (j <= l) ? sc[r] : 0.f;
                    sc[r] = m;
                    Aq[l * SA + j] = f2bf(m);      // masked score -> A for GEMM2
                }
            }
            rs += sc;                               // nt==4: rows 65..79 exact zeros
        }
        #pragma unroll
        for (int m = 1; m <= 8; m <<= 1) {          // row-sum across the 16 cols
            rs[0] += __shfl_xor(rs[0], m);
            rs[1] += __shfl_xor(rs[1], m);
            rs[2] += __shfl_xor(rs[2], m);
            rs[3] += __shfl_xor(rs[3], m);
        }
        #pragma unroll
        for (int r = 0; r < 4; ++r) inv[r] = 1.0f / fmaxf(rs[r], EPSV);
    }
    __syncthreads();   // make score writes unambiguously visible

    // ---- GEMM2: O = [scores | qf] * [V ; S] (waves 0-3, verified) ----
    if (wave < 4) {
        short8 sc0 = *(const short8*)&Aq[arow + 0 * 32 + quad * 8];
        short8 sc1 = *(const short8*)&Aq[arow + 1 * 32 + quad * 8];
        #pragma unroll
        for (int nt = 0; nt < 4; ++nt) {
            const int brow = (nt * 16 + lrow) * SV;
            floatx4 oacc = {0.f, 0.f, 0.f, 0.f};
            short8 b0 = *(const short8*)&Bv[brow + 0 * 32 + quad * 8];
            oacc = MFMA16(sc0, b0, oacc);
            short8 b1 = *(const short8*)&Bv[brow + 1 * 32 + quad * 8];
            oacc = MFMA16(sc1, b1, oacc);
            #pragma unroll
            for (int ks = 2; ks < 6; ++ks) {
                short8 bf = *(const short8*)&Bv[brow + ks * 32 + quad * 8];
                oacc = MFMA16(a1f[ks - 2], bf, oacc);
            }
            #pragma unroll
            for (int r = 0; r < 4; ++r) {
                int l = l0 + quad * 4 + r;
                out[gbase + (size_t)l * Dd + nt * 16 + lrow] = oacc[r] * inv[r];
            }
        }
    }
}

extern "C" void kernel_launch(void* const* d_in, const int* in_sizes, int n_in,
                              void* d_out, int out_size, void* d_ws, size_t ws_size,
                              hipStream_t stream) {
    const float* q = (const float*)d_in[0];
    const float* k = (const float*)d_in[1];
    const float* v = (const float*)d_in[2];
    float* out = (float*)d_out;
    unsigned short* wskv = (unsigned short*)d_ws;             // [h][c][d][f] bf16
    unsigned short* wsks = wskv + KV_TOTAL_E;                 // [h][c][128] bf16
    dim3 grid(NCHUNK, Hh);
    cf_sums<<<grid, 512, 0, stream>>>(k, v, wskv, wsks);
    cf_scan<<<dim3(33, Hh), 256, 0, stream>>>(wskv, wsks);
    cf_out<<<grid, 512, 0, stream>>>(q, k, v, wskv, wsks, out);
}